// Round 1
// baseline (567.768 us; speedup 1.0000x reference)
//
#include <hip/hip_runtime.h>
#include <math.h>

// Problem constants (MultiHeadAdapter: B=8,S=4096,H=8,D=128,K=32, fp32)
#define NB 8
#define NS 4096
#define NH 8
#define ND 128
#define NK 32
#define NT (NB*NS)          // 32768 tokens
#define HD (NH*ND)          // 1024

#define LN_EPS_F 1e-5f
#define BN_EPS_F 1e-5f
#define ADAPTER_SCALE 0.1f

#define BPH 64                               // blocks per head
#define THREADS 512
#define NWAVES (THREADS/64)                  // 8
#define TOK_PER_BLOCK (NT/BPH)               // 512
#define TOK_PER_WAVE (TOK_PER_BLOCK/NWAVES)  // 64

#define WDT_STRIDE 132                       // padded transposed w_down row stride (floats)

__global__ void zero_kernel(float* p, int n) {
    int i = blockIdx.x * blockDim.x + threadIdx.x;
    if (i < n) p[i] = 0.0f;
}

// MODE 0: compute pre-BN h, accumulate per-(h,d) sum / sumsq.
// MODE 1: recompute h, apply out = a*h + c + x (a,c fold BN+scale).
template <int MODE>
__global__ __launch_bounds__(THREADS)
void adapter_kernel(const float* __restrict__ x,
                    const float* __restrict__ ln_g, const float* __restrict__ ln_b,
                    const float* __restrict__ w_down, const float* __restrict__ b_down,
                    const float* __restrict__ w_up, const float* __restrict__ b_up,
                    float* __restrict__ gsum, float* __restrict__ gssq,
                    const float* __restrict__ avec, const float* __restrict__ cvec,
                    float* __restrict__ out)
{
    __shared__ float s_wdt[NK][WDT_STRIDE];   // w_down transposed [k][d], padded
    __shared__ float s_wup[NK][ND];           // w_up [k][d] (natural layout)
    __shared__ float s_lng[ND];
    __shared__ float s_lnb[ND];
    __shared__ float s_bd[NK];
    __shared__ float s_xn[NWAVES][ND];        // per-wave normalized row
    __shared__ float s_g[NWAVES][NK];         // per-wave GELU outputs
    __shared__ float s_red[2][NWAVES][ND];    // stats cross-wave reduce (MODE 0)

    const int h     = blockIdx.x / BPH;
    const int chunk = blockIdx.x % BPH;
    const int tid   = threadIdx.x;

    // Stage per-head weights into LDS
    for (int i = tid; i < ND*NK; i += THREADS) {
        const int d = i >> 5, k = i & 31;     // w_down[h][d][k]
        s_wdt[k][d] = w_down[h*ND*NK + i];
        (&s_wup[0][0])[i] = w_up[h*NK*ND + i];
    }
    if (tid < ND) { s_lng[tid] = ln_g[h*ND + tid]; s_lnb[tid] = ln_b[h*ND + tid]; }
    else if (tid < ND + NK) { const int k = tid - ND; s_bd[k] = b_down[h*NK + k]; }
    __syncthreads();

    const int wave = tid >> 6, lane = tid & 63;
    const int d0   = lane * 2;            // this lane owns features d0, d0+1
    const int k    = lane & 31;           // down-proj column
    const int hsel = lane >> 5;           // which half of D this lane dots

    const float2 bup2 = *(const float2*)(b_up + h*ND + d0);
    float2 a2 = make_float2(0.f, 0.f), c2 = make_float2(0.f, 0.f);
    if constexpr (MODE == 1) {
        a2 = *(const float2*)(avec + h*ND + d0);
        c2 = *(const float2*)(cvec + h*ND + d0);
    }
    float2 lsum = make_float2(0.f, 0.f), lssq = make_float2(0.f, 0.f);

    for (int it = 0; it < TOK_PER_WAVE; ++it) {
        const int t = chunk*TOK_PER_BLOCK + it*NWAVES + wave;
        const float* xp = x + (size_t)t*HD + h*ND;
        const float2 v = *(const float2*)(xp + d0);

        // ---- LayerNorm over D (wave shuffle reduction) ----
        float s1 = v.x + v.y;
        float s2 = v.x*v.x + v.y*v.y;
        #pragma unroll
        for (int off = 32; off > 0; off >>= 1) {
            s1 += __shfl_xor(s1, off);
            s2 += __shfl_xor(s2, off);
        }
        const float mu   = s1 * (1.0f/ND);
        const float var  = s2 * (1.0f/ND) - mu*mu;
        const float rstd = rsqrtf(var + LN_EPS_F);
        float2 xn;
        xn.x = (v.x - mu)*rstd*s_lng[d0]     + s_lnb[d0];
        xn.y = (v.y - mu)*rstd*s_lng[d0+1]   + s_lnb[d0+1];
        *(float2*)&s_xn[wave][d0] = xn;
        __builtin_amdgcn_wave_barrier();      // wave-private LDS buffer; order only

        // ---- down-proj: lane -> (k, half of D) half dot ----
        float acc = 0.f;
        #pragma unroll
        for (int d4 = 0; d4 < 16; ++d4) {
            const int d = hsel*64 + d4*4;
            const float4 xv = *(const float4*)&s_xn[wave][d];
            const float4 wv = *(const float4*)&s_wdt[k][d];
            acc = fmaf(xv.x, wv.x, acc);
            acc = fmaf(xv.y, wv.y, acc);
            acc = fmaf(xv.z, wv.z, acc);
            acc = fmaf(xv.w, wv.w, acc);
        }
        acc += __shfl_xor(acc, 32);           // combine the two half-dots
        acc += s_bd[k];
        const float gk = 0.5f*acc*(1.0f + erff(acc*0.70710678118654752f)); // exact GELU
        if (hsel == 0) s_g[wave][k] = gk;
        __builtin_amdgcn_wave_barrier();

        // ---- up-proj: lane computes features d0, d0+1 ----
        float2 o = bup2;
        #pragma unroll
        for (int kk = 0; kk < NK; ++kk) {
            const float gg = s_g[wave][kk];
            const float2 w2 = *(const float2*)&s_wup[kk][d0];
            o.x = fmaf(gg, w2.x, o.x);
            o.y = fmaf(gg, w2.y, o.y);
        }

        if constexpr (MODE == 0) {
            lsum.x += o.x;            lsum.y += o.y;
            lssq.x = fmaf(o.x, o.x, lssq.x);
            lssq.y = fmaf(o.y, o.y, lssq.y);
        } else {
            float2 r;
            r.x = fmaf(a2.x, o.x, c2.x + v.x);
            r.y = fmaf(a2.y, o.y, c2.y + v.y);
            *(float2*)(out + (size_t)t*HD + h*ND + d0) = r;
        }
    }

    if constexpr (MODE == 0) {
        // cross-wave reduce then one atomic per (h,d) per block
        s_red[0][wave][d0]   = lsum.x;  s_red[0][wave][d0+1] = lsum.y;
        s_red[1][wave][d0]   = lssq.x;  s_red[1][wave][d0+1] = lssq.y;
        __syncthreads();
        if (tid < 2*ND) {
            const int which = tid >> 7;       // 0 = sum, 1 = sumsq
            const int d     = tid & 127;
            float tot = 0.f;
            #pragma unroll
            for (int w = 0; w < NWAVES; ++w) tot += s_red[which][w][d];
            atomicAdd((which ? gssq : gsum) + h*ND + d, tot);
        }
    }
}

// Fold BN stats + affine + adapter scale into per-(h,d) a, c:
// out = a*h + c + x, a = 0.1*g/sqrt(var+eps), c = 0.1*(beta - mean*g/sqrt(var+eps))
__global__ void finalize_kernel(const float* __restrict__ gsum, const float* __restrict__ gssq,
                                const float* __restrict__ bn_g, const float* __restrict__ bn_b,
                                float* __restrict__ avec, float* __restrict__ cvec)
{
    const int i = blockIdx.x * blockDim.x + threadIdx.x;
    if (i < HD) {
        const float inv_n = 1.0f / (float)NT;
        const float mean = gsum[i] * inv_n;
        const float var  = gssq[i] * inv_n - mean*mean;
        const float rs   = rsqrtf(var + BN_EPS_F);
        const float a    = ADAPTER_SCALE * bn_g[i] * rs;
        avec[i] = a;
        cvec[i] = ADAPTER_SCALE * bn_b[i] - mean * a;
    }
}

extern "C" void kernel_launch(void* const* d_in, const int* in_sizes, int n_in,
                              void* d_out, int out_size, void* d_ws, size_t ws_size,
                              hipStream_t stream) {
    const float* x      = (const float*)d_in[0];
    const float* ln_g   = (const float*)d_in[1];
    const float* ln_b   = (const float*)d_in[2];
    const float* w_down = (const float*)d_in[3];
    const float* b_down = (const float*)d_in[4];
    const float* w_up   = (const float*)d_in[5];
    const float* b_up   = (const float*)d_in[6];
    const float* bn_g   = (const float*)d_in[7];
    const float* bn_b   = (const float*)d_in[8];
    float* out = (float*)d_out;

    float* ws   = (float*)d_ws;
    float* gsum = ws;            // [1024]
    float* gssq = ws + HD;       // [1024]
    float* avec = ws + 2*HD;     // [1024]
    float* cvec = ws + 3*HD;     // [1024]

    zero_kernel<<<(2*HD + 255)/256, 256, 0, stream>>>(gsum, 2*HD);
    adapter_kernel<0><<<NH*BPH, THREADS, 0, stream>>>(
        x, ln_g, ln_b, w_down, b_down, w_up, b_up,
        gsum, gssq, nullptr, nullptr, nullptr);
    finalize_kernel<<<(HD + 255)/256, 256, 0, stream>>>(gsum, gssq, bn_g, bn_b, avec, cvec);
    adapter_kernel<1><<<NH*BPH, THREADS, 0, stream>>>(
        x, ln_g, ln_b, w_down, b_down, w_up, b_up,
        nullptr, nullptr, avec, cvec, out);
}

// Round 2
// 381.755 us; speedup vs baseline: 1.4873x; 1.4873x over previous
//
#include <hip/hip_runtime.h>
#include <math.h>

// MultiHeadAdapter: B=8,S=4096,H=8,D=128,K=32, fp32 in/out
#define NB 8
#define NS 4096
#define NH 8
#define ND 128
#define NK 32
#define NT (NB*NS)          // 32768 tokens
#define HD (NH*ND)          // 1024

#define LN_EPS_F 1e-5f
#define BN_EPS_F 1e-5f
#define ADAPTER_SCALE 0.1f

#define THREADS 256
#define NWAVES 4
#define BPH 128                       // blocks per head
#define NBLK (NH*BPH)                 // 1024 blocks
#define TILES_PER_WAVE 4              // 16-token tiles per wave

typedef short short8 __attribute__((ext_vector_type(8)));
typedef float f32x4 __attribute__((ext_vector_type(4)));

__device__ inline unsigned short f2bf(float f) {
    union { float f; unsigned u; } v; v.f = f;
    unsigned r = v.u + 0x7fffu + ((v.u >> 16) & 1u);   // RNE
    return (unsigned short)(r >> 16);
}

__global__ void zero_kernel(float* p, int n) {
    int i = blockIdx.x * blockDim.x + threadIdx.x;
    if (i < n) p[i] = 0.0f;
}

// MODE 0: compute h (pre-BN), accumulate per-(h,d) sum/sumsq.
// MODE 1: recompute h, apply out = a*h + c + x.
template <int MODE>
__global__ __launch_bounds__(THREADS, 4)
void adapter_mfma(const float* __restrict__ x,
                  const float* __restrict__ ln_g, const float* __restrict__ ln_b,
                  const float* __restrict__ w_down, const float* __restrict__ b_down,
                  const float* __restrict__ w_up, const float* __restrict__ b_up,
                  float* __restrict__ gsum, float* __restrict__ gssq,
                  const float* __restrict__ avec, const float* __restrict__ cvec,
                  float* __restrict__ out)
{
    // per-wave activation buffers (bank-conflict-padded rows: 136 / 40 shorts)
    __shared__ __align__(16) unsigned short s_xn[NWAVES][16*136]; // LN(x) bf16, A-layout source
    __shared__ __align__(16) unsigned short s_gl[NWAVES][16*40];  // GELU out bf16
    __shared__ float s_stats[2][ND];

    const int h    = blockIdx.x & 7;
    const int bidx = blockIdx.x >> 3;      // 0..127
    const int tid  = threadIdx.x;
    const int wave = tid >> 6;
    const int lane = tid & 63;
    const int lg   = lane >> 4;            // 0..3  (k-group / row-group)
    const int lc   = lane & 15;            // 0..15 (column / row)

    if constexpr (MODE == 0) {
        if (tid < ND) { s_stats[0][tid] = 0.f; s_stats[1][tid] = 0.f; }
        __syncthreads();
    }

    // ---- weights -> MFMA B-fragments in registers (once per block) ----
    // B-frag convention: lane l holds B[k = 8*(l>>4)+i][n = l&15], i=0..7
    short8 wd[4][2];     // down: K=128 (4 steps of 32) x N=32 (2 tiles of 16)
    #pragma unroll
    for (int s = 0; s < 4; ++s)
        #pragma unroll
        for (int nt = 0; nt < 2; ++nt)
            #pragma unroll
            for (int i = 0; i < 8; ++i)
                wd[s][nt][i] = (short)f2bf(w_down[h*ND*NK + (32*s + 8*lg + i)*NK + 16*nt + lc]);
    short8 wu[8];        // up: K=32 x N=128 (8 tiles of 16)
    #pragma unroll
    for (int nt = 0; nt < 8; ++nt)
        #pragma unroll
        for (int i = 0; i < 8; ++i)
            wu[nt][i] = (short)f2bf(w_up[h*NK*ND + (8*lg + i)*ND + 16*nt + lc]);

    float bdreg[2];
    #pragma unroll
    for (int nt = 0; nt < 2; ++nt) bdreg[nt] = b_down[h*NK + 16*nt + lc];
    float bupreg[8];
    #pragma unroll
    for (int nt = 0; nt < 8; ++nt) bupreg[nt] = b_up[h*ND + 16*nt + lc];

    float areg[8], cfold[8];
    if constexpr (MODE == 1) {
        #pragma unroll
        for (int nt = 0; nt < 8; ++nt) {
            areg[nt]  = avec[h*ND + 16*nt + lc];
            cfold[nt] = fmaf(areg[nt], bupreg[nt], cvec[h*ND + 16*nt + lc]); // fold b_up
        }
    }

    const float2 lng2 = *(const float2*)(ln_g + h*ND + 2*lane);
    const float2 lnb2 = *(const float2*)(ln_b + h*ND + 2*lane);

    float sumacc[8], ssqacc[8];
    #pragma unroll
    for (int nt = 0; nt < 8; ++nt) { sumacc[nt] = 0.f; ssqacc[nt] = 0.f; }

    for (int it = 0; it < TILES_PER_WAVE; ++it) {
        const int tbase = bidx*256 + (wave + NWAVES*it)*16;

        // ---- LayerNorm: one token per iteration, wave-wide shuffle reduce ----
        for (int t = 0; t < 16; ++t) {
            const float2 v = *(const float2*)(x + (size_t)(tbase + t)*HD + h*ND + 2*lane);
            float s1 = v.x + v.y;
            float s2 = v.x*v.x + v.y*v.y;
            #pragma unroll
            for (int off = 32; off; off >>= 1) { s1 += __shfl_xor(s1, off); s2 += __shfl_xor(s2, off); }
            const float mu   = s1 * (1.0f/ND);
            const float rstd = rsqrtf(s2*(1.0f/ND) - mu*mu + LN_EPS_F);
            const float xa = (v.x - mu)*rstd*lng2.x + lnb2.x;
            const float xb = (v.y - mu)*rstd*lng2.y + lnb2.y;
            const unsigned pack = (unsigned)f2bf(xa) | ((unsigned)f2bf(xb) << 16);
            *(unsigned*)&s_xn[wave][t*136 + 2*lane] = pack;
        }
        __builtin_amdgcn_wave_barrier();

        // ---- A-fragments of LN(x): lane l holds A[l&15][k=8*(l>>4)+i] per K-step ----
        short8 ax[4];
        #pragma unroll
        for (int s = 0; s < 4; ++s)
            ax[s] = *(const short8*)&s_xn[wave][lc*136 + 32*s + 8*lg];

        // ---- down-proj MFMA + bias + exact GELU -> s_gl ----
        #pragma unroll
        for (int nt = 0; nt < 2; ++nt) {
            f32x4 acc = {0.f, 0.f, 0.f, 0.f};
            #pragma unroll
            for (int s = 0; s < 4; ++s)
                acc = __builtin_amdgcn_mfma_f32_16x16x32_bf16(ax[s], wd[s][nt], acc, 0, 0, 0);
            #pragma unroll
            for (int r = 0; r < 4; ++r) {
                const float vv = acc[r] + bdreg[nt];               // C/D: row=4*lg+r, col=lc
                const float ge = 0.5f*vv*(1.0f + erff(vv*0.70710678118654752f));
                s_gl[wave][(4*lg + r)*40 + 16*nt + lc] = f2bf(ge);
            }
        }
        __builtin_amdgcn_wave_barrier();

        // ---- up-proj: G (16x32) as A-frag, 8 N-tiles ----
        const short8 ag = *(const short8*)&s_gl[wave][lc*40 + 8*lg];
        #pragma unroll
        for (int nt = 0; nt < 8; ++nt) {
            f32x4 c2 = __builtin_amdgcn_mfma_f32_16x16x32_bf16(ag, wu[nt], (f32x4){0.f,0.f,0.f,0.f}, 0, 0, 0);
            if constexpr (MODE == 0) {
                #pragma unroll
                for (int r = 0; r < 4; ++r) {
                    const float hv = c2[r] + bupreg[nt];
                    sumacc[nt] += hv;
                    ssqacc[nt]  = fmaf(hv, hv, ssqacc[nt]);
                }
            } else {
                #pragma unroll
                for (int r = 0; r < 4; ++r) {
                    const size_t idx = (size_t)(tbase + 4*lg + r)*HD + h*ND + 16*nt + lc;
                    out[idx] = fmaf(areg[nt], c2[r], cfold[nt] + x[idx]);
                }
            }
        }
        __builtin_amdgcn_wave_barrier();   // before next tile overwrites s_xn/s_gl
    }

    if constexpr (MODE == 0) {
        #pragma unroll
        for (int nt = 0; nt < 8; ++nt) {
            atomicAdd(&s_stats[0][16*nt + lc], sumacc[nt]);
            atomicAdd(&s_stats[1][16*nt + lc], ssqacc[nt]);
        }
        __syncthreads();
        if (tid < ND) {
            atomicAdd(gsum + h*ND + tid, s_stats[0][tid]);
            atomicAdd(gssq + h*ND + tid, s_stats[1][tid]);
        }
    }
}

// out = a*h + c + x with a = 0.1*g*rsqrt(var+eps), c = 0.1*beta - mean*a
__global__ void finalize_kernel(const float* __restrict__ gsum, const float* __restrict__ gssq,
                                const float* __restrict__ bn_g, const float* __restrict__ bn_b,
                                float* __restrict__ avec, float* __restrict__ cvec)
{
    const int i = blockIdx.x * blockDim.x + threadIdx.x;
    if (i < HD) {
        const float inv_n = 1.0f / (float)NT;
        const float mean = gsum[i] * inv_n;
        const float var  = gssq[i] * inv_n - mean*mean;
        const float rs   = rsqrtf(var + BN_EPS_F);
        const float a    = ADAPTER_SCALE * bn_g[i] * rs;
        avec[i] = a;
        cvec[i] = ADAPTER_SCALE * bn_b[i] - mean * a;
    }
}

extern "C" void kernel_launch(void* const* d_in, const int* in_sizes, int n_in,
                              void* d_out, int out_size, void* d_ws, size_t ws_size,
                              hipStream_t stream) {
    const float* x      = (const float*)d_in[0];
    const float* ln_g   = (const float*)d_in[1];
    const float* ln_b   = (const float*)d_in[2];
    const float* w_down = (const float*)d_in[3];
    const float* b_down = (const float*)d_in[4];
    const float* w_up   = (const float*)d_in[5];
    const float* b_up   = (const float*)d_in[6];
    const float* bn_g   = (const float*)d_in[7];
    const float* bn_b   = (const float*)d_in[8];
    float* out = (float*)d_out;

    float* ws   = (float*)d_ws;
    float* gsum = ws;            // [1024]
    float* gssq = ws + HD;       // [1024]
    float* avec = ws + 2*HD;     // [1024]
    float* cvec = ws + 3*HD;     // [1024]

    zero_kernel<<<(2*HD + 255)/256, 256, 0, stream>>>(gsum, 2*HD);
    adapter_mfma<0><<<NBLK, THREADS, 0, stream>>>(
        x, ln_g, ln_b, w_down, b_down, w_up, b_up,
        gsum, gssq, nullptr, nullptr, nullptr);
    finalize_kernel<<<(HD + 255)/256, 256, 0, stream>>>(gsum, gssq, bn_g, bn_b, avec, cvec);
    adapter_mfma<1><<<NBLK, THREADS, 0, stream>>>(
        x, ln_g, ln_b, w_down, b_down, w_up, b_up,
        nullptr, nullptr, avec, cvec, out);
}